// Round 12
// baseline (3274.483 us; speedup 1.0000x reference)
//
#include <hip/hip_runtime.h>
#include <math.h>

#define DEPTH 4
#define C 128
#define P 17
#define HID 256
#define SPB 4            // 4 samples per block = 2 independent 34-row groups
#define GR 34            // rows per group
#define ROWS 68          // SPB*P
#define MT 3             // M tiles per 34-row group (48 padded; clamped)
#define LS 132           // fp32 LDS row stride
#define QS 136           // bf16 q/k/v row stride (avoids pow2 bank conflicts)
#define SEGQ (ROWS*QS)   // 9248
#define AS 264           // hi/lo bf16 row stride (128 hi | 128 lo | 8 pad)
#define ARENA_N (ROWS*AS) // 17952 shorts
#define NTHREADS 256

// workspace: W^T planes, row-major N x K, bf16. hi plane [0,524288), lo at +524288.
#define WTQ 0
#define WTP 196608
#define WT1 262144
#define WT2 393216
#define LO_OFF 524288

typedef short short8 __attribute__((ext_vector_type(8)));
typedef float f32x4 __attribute__((ext_vector_type(4)));

__device__ __forceinline__ unsigned short f2bf(float f) {
    unsigned int u = __float_as_uint(f);
    u += 0x7FFFu + ((u >> 16) & 1u);
    return (unsigned short)(u >> 16);
}
__device__ __forceinline__ float bf2f(unsigned short s) {
    return __uint_as_float((unsigned int)s << 16);
}
__device__ __forceinline__ void unpack8(uint4 u, float* f) {
    f[0] = __uint_as_float(u.x << 16); f[1] = __uint_as_float(u.x & 0xffff0000u);
    f[2] = __uint_as_float(u.y << 16); f[3] = __uint_as_float(u.y & 0xffff0000u);
    f[4] = __uint_as_float(u.z << 16); f[5] = __uint_as_float(u.z & 0xffff0000u);
    f[6] = __uint_as_float(u.w << 16); f[7] = __uint_as_float(u.w & 0xffff0000u);
}

// ---------------- prep: transpose W (KxN) -> WT (NxK row-major), hi+lo ----------------
extern "C" __global__ void prep_wt(const float* __restrict__ wq, const float* __restrict__ wp,
                                   const float* __restrict__ w1, const float* __restrict__ w2,
                                   unsigned short* __restrict__ ws) {
    int idx = blockIdx.x * 256 + threadIdx.x;   // grid 2048*256 = 524288 exactly
    int rel = idx; const float* W; int K, N;
    if (rel < 196608)                  { W = wq; K = 128; N = 384; }
    else if ((rel -= 196608) < 65536)  { W = wp; K = 128; N = 128; }
    else if ((rel -= 65536) < 131072)  { W = w1; K = 128; N = 256; }
    else { rel -= 131072;                W = w2; K = 256; N = 128; }
    int per = K * N;
    int l = rel / per, r = rel % per;
    int n = r / K, k = r % K;          // WT[n][k], k fastest
    float wv = W[l * per + k * N + n];
    unsigned short h = f2bf(wv);
    ws[idx] = h;
    ws[idx + LO_OFF] = f2bf(wv - bf2f(h));
}

// -------- dual-group MFMA GEMM: shares B fragments across G0/G1 (2 indep chains) -----
// Local A-rows >= GR are clamped (outputs discarded by epilogue guard): no junk reads.
template<int NTW, int KS>
__device__ __forceinline__ void gemm_bt2(const unsigned short* A0, const unsigned short* A1,
        int astride, int aLoOff,
        const unsigned short* __restrict__ WT, int ldk, int ntoff, int ksoff,
        int wave, int lane, f32x4 (&acc0)[MT][NTW], f32x4 (&acc1)[MT][NTW])
{
    int m = lane & 15, q = lane >> 4;
    int arow[MT];
    #pragma unroll
    for (int mt = 0; mt < MT; ++mt) {
        int ar = mt * 16 + m;
        arow[mt] = (ar >= GR) ? (ar - 16) : ar;   // 34..47 -> 18..31
    }
    for (int ks = 0; ks < KS; ++ks) {
        short8 ah0[MT], al0[MT], ah1[MT], al1[MT];
        #pragma unroll
        for (int mt = 0; mt < MT; ++mt) {
            int off = arow[mt] * astride + ks * 32 + q * 8;
            ah0[mt] = *(const short8*)&A0[off];
            al0[mt] = *(const short8*)&A0[off + aLoOff];
            ah1[mt] = *(const short8*)&A1[off];
            al1[mt] = *(const short8*)&A1[off + aLoOff];
        }
        #pragma unroll
        for (int nt = 0; nt < NTW; ++nt) {
            int nrow = (ntoff + wave * NTW + nt) * 16 + m;
            const unsigned short* bp = WT + nrow * ldk + (ksoff + ks) * 32 + q * 8;
            short8 bh = *(const short8*)bp;
            short8 bl = *(const short8*)(bp + LO_OFF);
            #pragma unroll
            for (int mt = 0; mt < MT; ++mt) {
                acc0[mt][nt] = __builtin_amdgcn_mfma_f32_16x16x32_bf16(ah0[mt], bh, acc0[mt][nt], 0, 0, 0);
                acc1[mt][nt] = __builtin_amdgcn_mfma_f32_16x16x32_bf16(ah1[mt], bh, acc1[mt][nt], 0, 0, 0);
                acc0[mt][nt] = __builtin_amdgcn_mfma_f32_16x16x32_bf16(al0[mt], bh, acc0[mt][nt], 0, 0, 0);
                acc1[mt][nt] = __builtin_amdgcn_mfma_f32_16x16x32_bf16(al1[mt], bh, acc1[mt][nt], 0, 0, 0);
                acc0[mt][nt] = __builtin_amdgcn_mfma_f32_16x16x32_bf16(ah0[mt], bl, acc0[mt][nt], 0, 0, 0);
                acc1[mt][nt] = __builtin_amdgcn_mfma_f32_16x16x32_bf16(ah1[mt], bl, acc1[mt][nt], 0, 0, 0);
            }
        }
    }
}

template<int NTW>
__device__ __forceinline__ void zero_acc(f32x4 (&acc)[MT][NTW]) {
    #pragma unroll
    for (int mt = 0; mt < MT; ++mt)
        #pragma unroll
        for (int nt = 0; nt < NTW; ++nt) acc[mt][nt] = (f32x4){0.f, 0.f, 0.f, 0.f};
}

// MODE 0 = ln1 (+gate), 1 = ln2 -> hi/lo bf16 DIRECTLY into arena; 2 = final->out.
template<int MODE>
__device__ __forceinline__ void ln_stage(const float* h_s, unsigned short* dst, float* gate_s,
        const float* __restrict__ g, const float* __restrict__ b,
        const float* __restrict__ wg, float bgate,
        float* __restrict__ outp, int tok0, int wave, int lane)
{
    int half = lane >> 5, l2 = lane & 31;
    #pragma unroll
    for (int it = 0; it < 9; ++it) {
        int row = it * 8 + wave * 2 + half;   // 0..71, each once
        if (row < ROWS) {
            float4 v = *(const float4*)&h_s[row * LS + l2 * 4];
            float s  = v.x + v.y + v.z + v.w;
            float ss = v.x*v.x + v.y*v.y + v.z*v.z + v.w*v.w;
            #pragma unroll
            for (int o = 16; o > 0; o >>= 1) { s += __shfl_xor(s, o, 32); ss += __shfl_xor(ss, o, 32); }
            float mean = s * (1.f / C);
            float rstd = rsqrtf(ss * (1.f / C) - mean * mean + 1e-6f);
            float4 gg = *(const float4*)&g[l2 * 4];
            float4 bb = *(const float4*)&b[l2 * 4];
            float e0 = (v.x - mean) * rstd * gg.x + bb.x;
            float e1 = (v.y - mean) * rstd * gg.y + bb.y;
            float e2 = (v.z - mean) * rstd * gg.z + bb.z;
            float e3 = (v.w - mean) * rstd * gg.w + bb.w;
            if (MODE == 2) {
                *(float4*)&outp[(tok0 + row) * C + l2 * 4] = make_float4(e0, e1, e2, e3);
            } else {
                unsigned short h0 = f2bf(e0), h1 = f2bf(e1), h2 = f2bf(e2), h3 = f2bf(e3);
                *(ushort4*)&dst[row * AS + l2 * 4] = make_ushort4(h0, h1, h2, h3);
                *(ushort4*)&dst[row * AS + 128 + l2 * 4] =
                    make_ushort4(f2bf(e0 - bf2f(h0)), f2bf(e1 - bf2f(h1)),
                                 f2bf(e2 - bf2f(h2)), f2bf(e3 - bf2f(h3)));
                if (MODE == 0) {
                    float4 wv = *(const float4*)&wg[l2 * 4];
                    float gp = e0*wv.x + e1*wv.y + e2*wv.z + e3*wv.w;
                    #pragma unroll
                    for (int o = 16; o > 0; o >>= 1) gp += __shfl_xor(gp, o, 32);
                    if (l2 == 0) gate_s[row] = 1.f / (1.f + expf(-(gp + bgate)));
                }
            }
        }
    }
}

// single-pass no-max softmax attention body for one (n, s, hh) pair of q-rows
// (or a single row when nB < 0). Stores o -> arena hi/lo.
__device__ __forceinline__ void attn_store(float* ov, float inv, unsigned short* op) {
    short8 h0, h1, l0, l1;
    #pragma unroll
    for (int d = 0; d < 8; ++d) {
        float va = ov[d] * inv, vb = ov[d + 8] * inv;
        unsigned short ha = f2bf(va), hb = f2bf(vb);
        h0[d] = (short)ha; h1[d] = (short)hb;
        l0[d] = (short)f2bf(va - bf2f(ha));
        l1[d] = (short)f2bf(vb - bf2f(hb));
    }
    *(short8*)&op[0]   = h0;
    *(short8*)&op[8]   = h1;
    *(short8*)&op[128] = l0;
    *(short8*)&op[136] = l1;
}

extern "C" __global__ __launch_bounds__(NTHREADS, 1)
void pose3d_r18(const float* __restrict__ x, const float* __restrict__ adj,
                 const float* __restrict__ w_embed, const float* __restrict__ b_embed,
                 const float* __restrict__ pos,
                 const float* __restrict__ ln1_g, const float* __restrict__ ln1_b,
                 const float* __restrict__ b_qkv,
                 const float* __restrict__ w_gate, const float* __restrict__ b_gate,
                 const float* __restrict__ b_proj,
                 const float* __restrict__ ln2_g, const float* __restrict__ ln2_b,
                 const float* __restrict__ b_fc1, const float* __restrict__ b_fc2,
                 const float* __restrict__ fn_g, const float* __restrict__ fn_b,
                 const unsigned short* __restrict__ wsw,
                 float* __restrict__ out)
{
    __shared__ __align__(16) float h_s[ROWS * LS];            // residual fp32 (35904 B)
    __shared__ __align__(16) unsigned short u_s[3 * SEGQ];    // q,k,v bf16 (55488 B); t aliases here in MLP
    __shared__ __align__(16) unsigned short arena[ARENA_N];   // hi/lo A-operands (35904 B)
    __shared__ float adj_s[P * P];
    __shared__ float gate_s[ROWS];

    const int tid = threadIdx.x;
    const int wave = tid >> 6, lane = tid & 63;
    const int m16 = lane & 15, q4 = lane >> 4;
    const int blk = blockIdx.x;

    // ---- embed (68 rows) ----
    for (int idx = tid; idx < ROWS * C; idx += NTHREADS) {
        int row = idx >> 7, c = idx & 127;
        int s = row / 17, p = row % 17;
        int xb = (blk * SPB + s) * (P * 2) + p * 2;
        h_s[row * LS + c] = x[xb] * w_embed[c] + x[xb + 1] * w_embed[C + c]
                          + b_embed[c] + pos[p * C + c];
    }
    for (int idx = tid; idx < P * P; idx += NTHREADS) adj_s[idx] = adj[idx];
    __syncthreads();

    const unsigned short* const ar0 = arena;
    const unsigned short* const ar1 = arena + GR * AS;

    for (int i = 0; i < DEPTH; ++i) {
        // ---- LN1 + gate -> arena hi/lo directly (both groups) ----
        ln_stage<0>(h_s, arena, gate_s, ln1_g + i * C, ln1_b + i * C,
                    w_gate + i * C, b_gate[i], nullptr, 0, wave, lane);
        __syncthreads();

        // ---- qkv GEMM: 2 passes of NTW=3, dual-group shared-B ----
        #pragma unroll
        for (int pass = 0; pass < 2; ++pass) {
            f32x4 acc0[MT][3], acc1[MT][3];
            zero_acc<3>(acc0); zero_acc<3>(acc1);
            gemm_bt2<3, 4>(ar0, ar1, AS, 128, wsw + WTQ + i * 49152, 128, pass * 12, 0,
                           wave, lane, acc0, acc1);
            const float* bq = b_qkv + i * 384;
            #pragma unroll
            for (int nt = 0; nt < 3; ++nt) {
                int n = (pass * 12 + wave * 3 + nt) * 16 + m16;
                float bias = bq[n];
                int t = n >> 7, cc = n & 127;
                #pragma unroll
                for (int mt = 0; mt < MT; ++mt)
                    #pragma unroll
                    for (int r = 0; r < 4; ++r) {
                        int row = mt * 16 + q4 * 4 + r;
                        if (row < GR) {
                            u_s[t * SEGQ + row * QS + cc]        = f2bf(acc0[mt][nt][r] + bias);
                            u_s[t * SEGQ + (GR + row) * QS + cc] = f2bf(acc1[mt][nt][r] + bias);
                        }
                    }
            }
        }
        __syncthreads();

        // ---- attention: paired tasks (tid, tid+256) share K/V rows;
        //      single-pass softmax without max-subtraction (scores bounded) ----
        {
            int nA = tid >> 5, sh = tid & 31;    // tasks tid and tid+256: same (s,hh), nB = nA+8
            int s = sh >> 3, hh = sh & 7;
            int nB = nA + 8;
            int base = s * 17;
            float qa[16], qb[16];
            { const uint4* qp = (const uint4*)&u_s[(base + nA) * QS + hh * 16];
              unpack8(qp[0], qa); unpack8(qp[1], qa + 8); }
            { const uint4* qp = (const uint4*)&u_s[(base + nB) * QS + hh * 16];
              unpack8(qp[0], qb); unpack8(qp[1], qb + 8); }
            float ova[16], ovb[16];
            #pragma unroll
            for (int d = 0; d < 16; ++d) { ova[d] = 0.f; ovb[d] = 0.f; }
            float suma = 0.f, sumb = 0.f;
            const unsigned short* kbase = &u_s[SEGQ + base * QS + hh * 16];
            const unsigned short* vbase = &u_s[2 * SEGQ + base * QS + hh * 16];
            uint4 k0 = *(const uint4*)kbase, k1 = *(const uint4*)(kbase + 8);
            uint4 v0 = *(const uint4*)vbase, v1 = *(const uint4*)(vbase + 8);
            #pragma unroll
            for (int mm = 0; mm < 17; ++mm) {
                uint4 pk0 = k0, pk1 = k1, pv0 = v0, pv1 = v1;
                if (mm < 16) {   // prefetch next K and V rows
                    pk0 = *(const uint4*)(kbase + (mm + 1) * QS);
                    pk1 = *(const uint4*)(kbase + (mm + 1) * QS + 8);
                    pv0 = *(const uint4*)(vbase + (mm + 1) * QS);
                    pv1 = *(const uint4*)(vbase + (mm + 1) * QS + 8);
                }
                float kf[16]; unpack8(k0, kf); unpack8(k1, kf + 8);
                float a0 = qa[0]*kf[0] + qa[4]*kf[4] + qa[8]*kf[8]   + qa[12]*kf[12];
                float a1 = qa[1]*kf[1] + qa[5]*kf[5] + qa[9]*kf[9]   + qa[13]*kf[13];
                float a2 = qa[2]*kf[2] + qa[6]*kf[6] + qa[10]*kf[10] + qa[14]*kf[14];
                float a3 = qa[3]*kf[3] + qa[7]*kf[7] + qa[11]*kf[11] + qa[15]*kf[15];
                float b0 = qb[0]*kf[0] + qb[4]*kf[4] + qb[8]*kf[8]   + qb[12]*kf[12];
                float b1 = qb[1]*kf[1] + qb[5]*kf[5] + qb[9]*kf[9]   + qb[13]*kf[13];
                float b2 = qb[2]*kf[2] + qb[6]*kf[6] + qb[10]*kf[10] + qb[14]*kf[14];
                float b3 = qb[3]*kf[3] + qb[7]*kf[7] + qb[11]*kf[11] + qb[15]*kf[15];
                float gt = gate_s[base + mm];
                float sc = 0.25f * (1.f - gt);
                float aa = ((a0 + a1) + (a2 + a3)) * sc + adj_s[nA * P + mm] * gt;
                float ab = ((b0 + b1) + (b2 + b3)) * sc + adj_s[nB * P + mm] * gt;
                float ea = __expf(aa), eb = __expf(ab);
                suma += ea; sumb += eb;
                float vf[16]; unpack8(v0, vf); unpack8(v1, vf + 8);
                #pragma unroll
                for (int d = 0; d < 16; ++d) { ova[d] += ea * vf[d]; ovb[d] += eb * vf[d]; }
                k0 = pk0; k1 = pk1; v0 = pv0; v1 = pv1;
            }
            attn_store(ova, 1.f / suma, &arena[(base + nA) * AS + hh * 16]);
            attn_store(ovb, 1.f / sumb, &arena[(base + nB) * AS + hh * 16]);
        }
        // third round: tasks 512..543 (n = 16), threads 0..31, single row
        if (tid < 32) {
            int s = tid >> 3, hh = tid & 7;
            int base = s * 17;
            const int n = 16;
            float qv[16];
            { const uint4* qp = (const uint4*)&u_s[(base + n) * QS + hh * 16];
              unpack8(qp[0], qv); unpack8(qp[1], qv + 8); }
            float ov[16];
            #pragma unroll
            for (int d = 0; d < 16; ++d) ov[d] = 0.f;
            float sum = 0.f;
            const unsigned short* kbase = &u_s[SEGQ + base * QS + hh * 16];
            const unsigned short* vbase = &u_s[2 * SEGQ + base * QS + hh * 16];
            uint4 k0 = *(const uint4*)kbase, k1 = *(const uint4*)(kbase + 8);
            uint4 v0 = *(const uint4*)vbase, v1 = *(const uint4*)(vbase + 8);
            #pragma unroll
            for (int mm = 0; mm < 17; ++mm) {
                uint4 pk0 = k0, pk1 = k1, pv0 = v0, pv1 = v1;
                if (mm < 16) {
                    pk0 = *(const uint4*)(kbase + (mm + 1) * QS);
                    pk1 = *(const uint4*)(kbase + (mm + 1) * QS + 8);
                    pv0 = *(const uint4*)(vbase + (mm + 1) * QS);
                    pv1 = *(const uint4*)(vbase + (mm + 1) * QS + 8);
                }
                float kf[16]; unpack8(k0, kf); unpack8(k1, kf + 8);
                float a0 = qv[0]*kf[0] + qv[4]*kf[4] + qv[8]*kf[8]   + qv[12]*kf[12];
                float a1 = qv[1]*kf[1] + qv[5]*kf[5] + qv[9]*kf[9]   + qv[13]*kf[13];
                float a2 = qv[2]*kf[2] + qv[6]*kf[6] + qv[10]*kf[10] + qv[14]*kf[14];
                float a3 = qv[3]*kf[3] + qv[7]*kf[7] + qv[11]*kf[11] + qv[15]*kf[15];
                float gt = gate_s[base + mm];
                float aa = ((a0 + a1) + (a2 + a3)) * 0.25f * (1.f - gt) + adj_s[n * P + mm] * gt;
                float ea = __expf(aa);
                sum += ea;
                float vf[16]; unpack8(v0, vf); unpack8(v1, vf + 8);
                #pragma unroll
                for (int d = 0; d < 16; ++d) ov[d] += ea * vf[d];
                k0 = pk0; k1 = pk1; v0 = pv0; v1 = pv1;
            }
            attn_store(ov, 1.f / sum, &arena[(base + n) * AS + hh * 16]);
        }
        __syncthreads();

        // ---- proj GEMM dual-group (NTW=2) + residual into h_s ----
        {
            f32x4 acc0[MT][2], acc1[MT][2];
            zero_acc<2>(acc0); zero_acc<2>(acc1);
            gemm_bt2<2, 4>(ar0, ar1, AS, 128, wsw + WTP + i * 16384, 128, 0, 0,
                           wave, lane, acc0, acc1);
            const float* bp = b_proj + i * C;
            #pragma unroll
            for (int nt = 0; nt < 2; ++nt) {
                int n = (wave * 2 + nt) * 16 + m16;
                float bias = bp[n];
                #pragma unroll
                for (int mt = 0; mt < MT; ++mt)
                    #pragma unroll
                    for (int r = 0; r < 4; ++r) {
                        int row = mt * 16 + q4 * 4 + r;
                        if (row < GR) {
                            h_s[row * LS + n]        += acc0[mt][nt][r] + bias;
                            h_s[(GR + row) * LS + n] += acc1[mt][nt][r] + bias;
                        }
                    }
            }
        }
        __syncthreads();

        // ---- LN2 -> arena hi/lo directly ----
        ln_stage<1>(h_s, arena, gate_s, ln2_g + i * C, ln2_b + i * C,
                    nullptr, 0.f, nullptr, 0, wave, lane);
        __syncthreads();

        // ---- MLP dual-group (r14 proven 5-barrier form); t aliases u_s ----
        {
            const unsigned short* const t0 = u_s;
            const unsigned short* const t1 = u_s + GR * AS;
            f32x4 acc20[MT][2], acc21[MT][2];
            zero_acc<2>(acc20); zero_acc<2>(acc21);
            for (int hf = 0; hf < 2; ++hf) {
                f32x4 acc10[MT][2], acc11[MT][2];
                zero_acc<2>(acc10); zero_acc<2>(acc11);
                gemm_bt2<2, 4>(ar0, ar1, AS, 128, wsw + WT1 + i * 32768, 128, hf * 8, 0,
                               wave, lane, acc10, acc11);
                const float* b1 = b_fc1 + i * HID + hf * 128;
                #pragma unroll
                for (int nt = 0; nt < 2; ++nt) {
                    int nl = (wave * 2 + nt) * 16 + m16;
                    float bias = b1[nl];
                    #pragma unroll
                    for (int mt = 0; mt < MT; ++mt)
                        #pragma unroll
                        for (int r = 0; r < 4; ++r) {
                            int row = mt * 16 + q4 * 4 + r;
                            if (row < GR) {
                                float xx = acc10[mt][nt][r] + bias;
                                float ge = 0.5f * xx * (1.f + erff(xx * 0.70710678118654752f));
                                unsigned short hb = f2bf(ge);
                                u_s[row * AS + nl] = hb;
                                u_s[row * AS + 128 + nl] = f2bf(ge - bf2f(hb));
                                float xx1 = acc11[mt][nt][r] + bias;
                                float ge1 = 0.5f * xx1 * (1.f + erff(xx1 * 0.70710678118654752f));
                                unsigned short hb1 = f2bf(ge1);
                                u_s[(GR + row) * AS + nl] = hb1;
                                u_s[(GR + row) * AS + 128 + nl] = f2bf(ge1 - bf2f(hb1));
                            }
                        }
                }
                __syncthreads();   // t half visible
                gemm_bt2<2, 4>(t0, t1, AS, 128, wsw + WT2 + i * 32768, 256, 0, hf * 4,
                               wave, lane, acc20, acc21);
                __syncthreads();   // done reading t before next half overwrites
            }
            const float* b2 = b_fc2 + i * C;
            #pragma unroll
            for (int nt = 0; nt < 2; ++nt) {
                int n = (wave * 2 + nt) * 16 + m16;
                float bias = b2[n];
                #pragma unroll
                for (int mt = 0; mt < MT; ++mt)
                    #pragma unroll
                    for (int r = 0; r < 4; ++r) {
                        int row = mt * 16 + q4 * 4 + r;
                        if (row < GR) {
                            h_s[row * LS + n]        += acc20[mt][nt][r] + bias;
                            h_s[(GR + row) * LS + n] += acc21[mt][nt][r] + bias;
                        }
                    }
            }
        }
        __syncthreads();
    }

    // ---- final LN -> out ----
    ln_stage<2>(h_s, nullptr, nullptr, fn_g, fn_b, nullptr, 0.f, out, blk * ROWS, wave, lane);
}

extern "C" void kernel_launch(void* const* d_in, const int* in_sizes, int n_in,
                              void* d_out, int out_size, void* d_ws, size_t ws_size,
                              hipStream_t stream) {
    const float* x       = (const float*)d_in[0];
    const float* adj     = (const float*)d_in[1];
    const float* w_embed = (const float*)d_in[2];
    const float* b_embed = (const float*)d_in[3];
    const float* pos     = (const float*)d_in[4];
    const float* ln1_g   = (const float*)d_in[5];
    const float* ln1_b   = (const float*)d_in[6];
    const float* w_qkv   = (const float*)d_in[7];
    const float* b_qkv   = (const float*)d_in[8];
    const float* w_gate  = (const float*)d_in[9];
    const float* b_gate  = (const float*)d_in[10];
    const float* w_proj  = (const float*)d_in[11];
    const float* b_proj  = (const float*)d_in[12];
    const float* ln2_g   = (const float*)d_in[13];
    const float* ln2_b   = (const float*)d_in[14];
    const float* w_fc1   = (const float*)d_in[15];
    const float* b_fc1   = (const float*)d_in[16];
    const float* w_fc2   = (const float*)d_in[17];
    const float* b_fc2   = (const float*)d_in[18];
    const float* fn_g    = (const float*)d_in[19];
    const float* fn_b    = (const float*)d_in[20];
    unsigned short* ws   = (unsigned short*)d_ws;   // 2 MiB
    float* out = (float*)d_out;

    prep_wt<<<2048, 256, 0, stream>>>(w_qkv, w_proj, w_fc1, w_fc2, ws);
    pose3d_r18<<<1944, NTHREADS, 0, stream>>>(x, adj, w_embed, b_embed, pos,
        ln1_g, ln1_b, b_qkv, w_gate, b_gate, b_proj, ln2_g, ln2_b,
        b_fc1, b_fc2, fn_g, fn_b, ws, out);
}

// Round 13
// 2694.261 us; speedup vs baseline: 1.2154x; 1.2154x over previous
//
#include <hip/hip_runtime.h>
#include <math.h>

#define DEPTH 4
#define C 128
#define P 17
#define HID 256
#define SPB 4            // 4 samples per block = 2 independent 34-row groups
#define GR 34            // rows per group
#define ROWS 68          // SPB*P
#define MT 3             // M tiles per 34-row group (48 padded; clamped)
#define LS 132           // fp32 LDS row stride
#define QS 136           // bf16 q/k/v row stride (avoids pow2 bank conflicts)
#define SEGQ (ROWS*QS)   // 9248
#define AS 264           // hi/lo bf16 row stride (128 hi | 128 lo | 8 pad)
#define ARENA_N (ROWS*AS) // 17952 shorts
#define NTHREADS 256

// workspace: W^T planes, row-major N x K, bf16. hi plane [0,524288), lo at +524288.
#define WTQ 0
#define WTP 196608
#define WT1 262144
#define WT2 393216
#define LO_OFF 524288

typedef short short8 __attribute__((ext_vector_type(8)));
typedef float f32x4 __attribute__((ext_vector_type(4)));

__device__ __forceinline__ unsigned short f2bf(float f) {
    unsigned int u = __float_as_uint(f);
    u += 0x7FFFu + ((u >> 16) & 1u);
    return (unsigned short)(u >> 16);
}
__device__ __forceinline__ float bf2f(unsigned short s) {
    return __uint_as_float((unsigned int)s << 16);
}
__device__ __forceinline__ void unpack8(uint4 u, float* f) {
    f[0] = __uint_as_float(u.x << 16); f[1] = __uint_as_float(u.x & 0xffff0000u);
    f[2] = __uint_as_float(u.y << 16); f[3] = __uint_as_float(u.y & 0xffff0000u);
    f[4] = __uint_as_float(u.z << 16); f[5] = __uint_as_float(u.z & 0xffff0000u);
    f[6] = __uint_as_float(u.w << 16); f[7] = __uint_as_float(u.w & 0xffff0000u);
}

// ---------------- prep: transpose W (KxN) -> WT (NxK row-major), hi+lo ----------------
extern "C" __global__ void prep_wt(const float* __restrict__ wq, const float* __restrict__ wp,
                                   const float* __restrict__ w1, const float* __restrict__ w2,
                                   unsigned short* __restrict__ ws) {
    int idx = blockIdx.x * 256 + threadIdx.x;   // grid 2048*256 = 524288 exactly
    int rel = idx; const float* W; int K, N;
    if (rel < 196608)                  { W = wq; K = 128; N = 384; }
    else if ((rel -= 196608) < 65536)  { W = wp; K = 128; N = 128; }
    else if ((rel -= 65536) < 131072)  { W = w1; K = 128; N = 256; }
    else { rel -= 131072;                W = w2; K = 256; N = 128; }
    int per = K * N;
    int l = rel / per, r = rel % per;
    int n = r / K, k = r % K;          // WT[n][k], k fastest
    float wv = W[l * per + k * N + n];
    unsigned short h = f2bf(wv);
    ws[idx] = h;
    ws[idx + LO_OFF] = f2bf(wv - bf2f(h));
}

// -------- dual-group MFMA GEMM: shares B fragments across G0/G1 (2 indep chains) -----
// Local A-rows >= GR are clamped (outputs discarded by epilogue guard): no junk reads.
template<int NTW, int KS>
__device__ __forceinline__ void gemm_bt2(const unsigned short* A0, const unsigned short* A1,
        int astride, int aLoOff,
        const unsigned short* __restrict__ WT, int ldk, int ntoff, int ksoff,
        int wave, int lane, f32x4 (&acc0)[MT][NTW], f32x4 (&acc1)[MT][NTW])
{
    int m = lane & 15, q = lane >> 4;
    int arow[MT];
    #pragma unroll
    for (int mt = 0; mt < MT; ++mt) {
        int ar = mt * 16 + m;
        arow[mt] = (ar >= GR) ? (ar - 16) : ar;   // 34..47 -> 18..31
    }
    for (int ks = 0; ks < KS; ++ks) {
        short8 ah0[MT], al0[MT], ah1[MT], al1[MT];
        #pragma unroll
        for (int mt = 0; mt < MT; ++mt) {
            int off = arow[mt] * astride + ks * 32 + q * 8;
            ah0[mt] = *(const short8*)&A0[off];
            al0[mt] = *(const short8*)&A0[off + aLoOff];
            ah1[mt] = *(const short8*)&A1[off];
            al1[mt] = *(const short8*)&A1[off + aLoOff];
        }
        #pragma unroll
        for (int nt = 0; nt < NTW; ++nt) {
            int nrow = (ntoff + wave * NTW + nt) * 16 + m;
            const unsigned short* bp = WT + nrow * ldk + (ksoff + ks) * 32 + q * 8;
            short8 bh = *(const short8*)bp;
            short8 bl = *(const short8*)(bp + LO_OFF);
            #pragma unroll
            for (int mt = 0; mt < MT; ++mt) {
                acc0[mt][nt] = __builtin_amdgcn_mfma_f32_16x16x32_bf16(ah0[mt], bh, acc0[mt][nt], 0, 0, 0);
                acc1[mt][nt] = __builtin_amdgcn_mfma_f32_16x16x32_bf16(ah1[mt], bh, acc1[mt][nt], 0, 0, 0);
                acc0[mt][nt] = __builtin_amdgcn_mfma_f32_16x16x32_bf16(al0[mt], bh, acc0[mt][nt], 0, 0, 0);
                acc1[mt][nt] = __builtin_amdgcn_mfma_f32_16x16x32_bf16(al1[mt], bh, acc1[mt][nt], 0, 0, 0);
                acc0[mt][nt] = __builtin_amdgcn_mfma_f32_16x16x32_bf16(ah0[mt], bl, acc0[mt][nt], 0, 0, 0);
                acc1[mt][nt] = __builtin_amdgcn_mfma_f32_16x16x32_bf16(ah1[mt], bl, acc1[mt][nt], 0, 0, 0);
            }
        }
    }
}

template<int NTW>
__device__ __forceinline__ void zero_acc(f32x4 (&acc)[MT][NTW]) {
    #pragma unroll
    for (int mt = 0; mt < MT; ++mt)
        #pragma unroll
        for (int nt = 0; nt < NTW; ++nt) acc[mt][nt] = (f32x4){0.f, 0.f, 0.f, 0.f};
}

// MODE 0 = ln1 (+gate), 1 = ln2 -> hi/lo bf16 DIRECTLY into arena; 2 = final->out.
template<int MODE>
__device__ __forceinline__ void ln_stage(const float* h_s, unsigned short* dst, float* gate_s,
        const float* __restrict__ g, const float* __restrict__ b,
        const float* __restrict__ wg, float bgate,
        float* __restrict__ outp, int tok0, int wave, int lane)
{
    int half = lane >> 5, l2 = lane & 31;
    #pragma unroll
    for (int it = 0; it < 9; ++it) {
        int row = it * 8 + wave * 2 + half;   // 0..71, each once
        if (row < ROWS) {
            float4 v = *(const float4*)&h_s[row * LS + l2 * 4];
            float s  = v.x + v.y + v.z + v.w;
            float ss = v.x*v.x + v.y*v.y + v.z*v.z + v.w*v.w;
            #pragma unroll
            for (int o = 16; o > 0; o >>= 1) { s += __shfl_xor(s, o, 32); ss += __shfl_xor(ss, o, 32); }
            float mean = s * (1.f / C);
            float rstd = rsqrtf(ss * (1.f / C) - mean * mean + 1e-6f);
            float4 gg = *(const float4*)&g[l2 * 4];
            float4 bb = *(const float4*)&b[l2 * 4];
            float e0 = (v.x - mean) * rstd * gg.x + bb.x;
            float e1 = (v.y - mean) * rstd * gg.y + bb.y;
            float e2 = (v.z - mean) * rstd * gg.z + bb.z;
            float e3 = (v.w - mean) * rstd * gg.w + bb.w;
            if (MODE == 2) {
                *(float4*)&outp[(tok0 + row) * C + l2 * 4] = make_float4(e0, e1, e2, e3);
            } else {
                unsigned short h0 = f2bf(e0), h1 = f2bf(e1), h2 = f2bf(e2), h3 = f2bf(e3);
                *(ushort4*)&dst[row * AS + l2 * 4] = make_ushort4(h0, h1, h2, h3);
                *(ushort4*)&dst[row * AS + 128 + l2 * 4] =
                    make_ushort4(f2bf(e0 - bf2f(h0)), f2bf(e1 - bf2f(h1)),
                                 f2bf(e2 - bf2f(h2)), f2bf(e3 - bf2f(h3)));
                if (MODE == 0) {
                    float4 wv = *(const float4*)&wg[l2 * 4];
                    float gp = e0*wv.x + e1*wv.y + e2*wv.z + e3*wv.w;
                    #pragma unroll
                    for (int o = 16; o > 0; o >>= 1) gp += __shfl_xor(gp, o, 32);
                    if (l2 == 0) gate_s[row] = 1.f / (1.f + expf(-(gp + bgate)));
                }
            }
        }
    }
}

__device__ __forceinline__ void attn_store(float* ov, float inv, unsigned short* op) {
    short8 h0, h1, l0, l1;
    #pragma unroll
    for (int d = 0; d < 8; ++d) {
        float va = ov[d] * inv, vb = ov[d + 8] * inv;
        unsigned short ha = f2bf(va), hb = f2bf(vb);
        h0[d] = (short)ha; h1[d] = (short)hb;
        l0[d] = (short)f2bf(va - bf2f(ha));
        l1[d] = (short)f2bf(vb - bf2f(hb));
    }
    *(short8*)&op[0]   = h0;
    *(short8*)&op[8]   = h1;
    *(short8*)&op[128] = l0;
    *(short8*)&op[136] = l1;
}

extern "C" __global__ __launch_bounds__(NTHREADS, 1)
void pose3d_r19(const float* __restrict__ x, const float* __restrict__ adj,
                 const float* __restrict__ w_embed, const float* __restrict__ b_embed,
                 const float* __restrict__ pos,
                 const float* __restrict__ ln1_g, const float* __restrict__ ln1_b,
                 const float* __restrict__ b_qkv,
                 const float* __restrict__ w_gate, const float* __restrict__ b_gate,
                 const float* __restrict__ b_proj,
                 const float* __restrict__ ln2_g, const float* __restrict__ ln2_b,
                 const float* __restrict__ b_fc1, const float* __restrict__ b_fc2,
                 const float* __restrict__ fn_g, const float* __restrict__ fn_b,
                 const unsigned short* __restrict__ wsw,
                 float* __restrict__ out)
{
    __shared__ __align__(16) float h_s[ROWS * LS];            // residual fp32 (35904 B)
    __shared__ __align__(16) unsigned short u_s[3 * SEGQ];    // q,k,v bf16 (55488 B); t aliases here in MLP
    __shared__ __align__(16) unsigned short arena[ARENA_N];   // hi/lo A-operands (35904 B)
    __shared__ float adj_s[P * P];
    __shared__ float gate_s[ROWS];

    const int tid = threadIdx.x;
    const int wave = tid >> 6, lane = tid & 63;
    const int m16 = lane & 15, q4 = lane >> 4;
    const int blk = blockIdx.x;

    // ---- embed (68 rows) ----
    for (int idx = tid; idx < ROWS * C; idx += NTHREADS) {
        int row = idx >> 7, c = idx & 127;
        int s = row / 17, p = row % 17;
        int xb = (blk * SPB + s) * (P * 2) + p * 2;
        h_s[row * LS + c] = x[xb] * w_embed[c] + x[xb + 1] * w_embed[C + c]
                          + b_embed[c] + pos[p * C + c];
    }
    for (int idx = tid; idx < P * P; idx += NTHREADS) adj_s[idx] = adj[idx];
    __syncthreads();

    const unsigned short* const ar0 = arena;
    const unsigned short* const ar1 = arena + GR * AS;

    for (int i = 0; i < DEPTH; ++i) {
        // ---- LN1 + gate -> arena hi/lo directly (both groups) ----
        ln_stage<0>(h_s, arena, gate_s, ln1_g + i * C, ln1_b + i * C,
                    w_gate + i * C, b_gate[i], nullptr, 0, wave, lane);
        __syncthreads();

        // ---- qkv GEMM: 2 passes of NTW=3, dual-group shared-B ----
        #pragma unroll
        for (int pass = 0; pass < 2; ++pass) {
            f32x4 acc0[MT][3], acc1[MT][3];
            zero_acc<3>(acc0); zero_acc<3>(acc1);
            gemm_bt2<3, 4>(ar0, ar1, AS, 128, wsw + WTQ + i * 49152, 128, pass * 12, 0,
                           wave, lane, acc0, acc1);
            const float* bq = b_qkv + i * 384;
            #pragma unroll
            for (int nt = 0; nt < 3; ++nt) {
                int n = (pass * 12 + wave * 3 + nt) * 16 + m16;
                float bias = bq[n];
                int t = n >> 7, cc = n & 127;
                #pragma unroll
                for (int mt = 0; mt < MT; ++mt)
                    #pragma unroll
                    for (int r = 0; r < 4; ++r) {
                        int row = mt * 16 + q4 * 4 + r;
                        if (row < GR) {
                            u_s[t * SEGQ + row * QS + cc]        = f2bf(acc0[mt][nt][r] + bias);
                            u_s[t * SEGQ + (GR + row) * QS + cc] = f2bf(acc1[mt][nt][r] + bias);
                        }
                    }
            }
        }
        __syncthreads();

        // ---- attention (VALU): 544 tasks, UNPAIRED single-pass no-max softmax;
        //      fused QK->exp->PV loop, K and V rows prefetched one-ahead ----
        for (int task = tid; task < 544; task += NTHREADS) {
            int n = task >> 5, sh = task & 31;       // n 0..16
            int s = sh >> 3, hh = sh & 7;            // s 0..3, hh 0..7
            int base = s * 17;
            float qv[16];
            { const uint4* qp = (const uint4*)&u_s[(base + n) * QS + hh * 16];
              unpack8(qp[0], qv); unpack8(qp[1], qv + 8); }
            float ov[16];
            #pragma unroll
            for (int d = 0; d < 16; ++d) ov[d] = 0.f;
            float sum = 0.f;
            const unsigned short* kbase = &u_s[SEGQ + base * QS + hh * 16];
            const unsigned short* vbase = &u_s[2 * SEGQ + base * QS + hh * 16];
            uint4 k0 = *(const uint4*)kbase, k1 = *(const uint4*)(kbase + 8);
            uint4 v0 = *(const uint4*)vbase, v1 = *(const uint4*)(vbase + 8);
            #pragma unroll
            for (int mm = 0; mm < 17; ++mm) {
                uint4 pk0 = k0, pk1 = k1, pv0 = v0, pv1 = v1;
                if (mm < 16) {   // prefetch next K and V rows
                    pk0 = *(const uint4*)(kbase + (mm + 1) * QS);
                    pk1 = *(const uint4*)(kbase + (mm + 1) * QS + 8);
                    pv0 = *(const uint4*)(vbase + (mm + 1) * QS);
                    pv1 = *(const uint4*)(vbase + (mm + 1) * QS + 8);
                }
                float kf[16]; unpack8(k0, kf); unpack8(k1, kf + 8);
                float a0 = qv[0]*kf[0] + qv[4]*kf[4] + qv[8]*kf[8]   + qv[12]*kf[12];
                float a1 = qv[1]*kf[1] + qv[5]*kf[5] + qv[9]*kf[9]   + qv[13]*kf[13];
                float a2 = qv[2]*kf[2] + qv[6]*kf[6] + qv[10]*kf[10] + qv[14]*kf[14];
                float a3 = qv[3]*kf[3] + qv[7]*kf[7] + qv[11]*kf[11] + qv[15]*kf[15];
                float gt = gate_s[base + mm];
                float aa = ((a0 + a1) + (a2 + a3)) * 0.25f * (1.f - gt) + adj_s[n * P + mm] * gt;
                float ea = __expf(aa);
                sum += ea;
                float vf[16]; unpack8(v0, vf); unpack8(v1, vf + 8);
                #pragma unroll
                for (int d = 0; d < 16; ++d) ov[d] += ea * vf[d];
                k0 = pk0; k1 = pk1; v0 = pv0; v1 = pv1;
            }
            attn_store(ov, 1.f / sum, &arena[(base + n) * AS + hh * 16]);
        }
        __syncthreads();

        // ---- proj GEMM dual-group (NTW=2) + residual into h_s ----
        {
            f32x4 acc0[MT][2], acc1[MT][2];
            zero_acc<2>(acc0); zero_acc<2>(acc1);
            gemm_bt2<2, 4>(ar0, ar1, AS, 128, wsw + WTP + i * 16384, 128, 0, 0,
                           wave, lane, acc0, acc1);
            const float* bp = b_proj + i * C;
            #pragma unroll
            for (int nt = 0; nt < 2; ++nt) {
                int n = (wave * 2 + nt) * 16 + m16;
                float bias = bp[n];
                #pragma unroll
                for (int mt = 0; mt < MT; ++mt)
                    #pragma unroll
                    for (int r = 0; r < 4; ++r) {
                        int row = mt * 16 + q4 * 4 + r;
                        if (row < GR) {
                            h_s[row * LS + n]        += acc0[mt][nt][r] + bias;
                            h_s[(GR + row) * LS + n] += acc1[mt][nt][r] + bias;
                        }
                    }
            }
        }
        __syncthreads();

        // ---- LN2 -> arena hi/lo directly ----
        ln_stage<1>(h_s, arena, gate_s, ln2_g + i * C, ln2_b + i * C,
                    nullptr, 0.f, nullptr, 0, wave, lane);
        __syncthreads();

        // ---- MLP dual-group (r14 proven 5-barrier form); t aliases u_s ----
        {
            const unsigned short* const t0 = u_s;
            const unsigned short* const t1 = u_s + GR * AS;
            f32x4 acc20[MT][2], acc21[MT][2];
            zero_acc<2>(acc20); zero_acc<2>(acc21);
            for (int hf = 0; hf < 2; ++hf) {
                f32x4 acc10[MT][2], acc11[MT][2];
                zero_acc<2>(acc10); zero_acc<2>(acc11);
                gemm_bt2<2, 4>(ar0, ar1, AS, 128, wsw + WT1 + i * 32768, 128, hf * 8, 0,
                               wave, lane, acc10, acc11);
                const float* b1 = b_fc1 + i * HID + hf * 128;
                #pragma unroll
                for (int nt = 0; nt < 2; ++nt) {
                    int nl = (wave * 2 + nt) * 16 + m16;
                    float bias = b1[nl];
                    #pragma unroll
                    for (int mt = 0; mt < MT; ++mt)
                        #pragma unroll
                        for (int r = 0; r < 4; ++r) {
                            int row = mt * 16 + q4 * 4 + r;
                            if (row < GR) {
                                float xx = acc10[mt][nt][r] + bias;
                                float ge = 0.5f * xx * (1.f + erff(xx * 0.70710678118654752f));
                                unsigned short hb = f2bf(ge);
                                u_s[row * AS + nl] = hb;
                                u_s[row * AS + 128 + nl] = f2bf(ge - bf2f(hb));
                                float xx1 = acc11[mt][nt][r] + bias;
                                float ge1 = 0.5f * xx1 * (1.f + erff(xx1 * 0.70710678118654752f));
                                unsigned short hb1 = f2bf(ge1);
                                u_s[(GR + row) * AS + nl] = hb1;
                                u_s[(GR + row) * AS + 128 + nl] = f2bf(ge1 - bf2f(hb1));
                            }
                        }
                }
                __syncthreads();   // t half visible
                gemm_bt2<2, 4>(t0, t1, AS, 128, wsw + WT2 + i * 32768, 256, 0, hf * 4,
                               wave, lane, acc20, acc21);
                __syncthreads();   // done reading t before next half overwrites
            }
            const float* b2 = b_fc2 + i * C;
            #pragma unroll
            for (int nt = 0; nt < 2; ++nt) {
                int n = (wave * 2 + nt) * 16 + m16;
                float bias = b2[n];
                #pragma unroll
                for (int mt = 0; mt < MT; ++mt)
                    #pragma unroll
                    for (int r = 0; r < 4; ++r) {
                        int row = mt * 16 + q4 * 4 + r;
                        if (row < GR) {
                            h_s[row * LS + n]        += acc20[mt][nt][r] + bias;
                            h_s[(GR + row) * LS + n] += acc21[mt][nt][r] + bias;
                        }
                    }
            }
        }
        __syncthreads();
    }

    // ---- final LN -> out ----
    ln_stage<2>(h_s, nullptr, nullptr, fn_g, fn_b, nullptr, 0.f, out, blk * ROWS, wave, lane);
}

extern "C" void kernel_launch(void* const* d_in, const int* in_sizes, int n_in,
                              void* d_out, int out_size, void* d_ws, size_t ws_size,
                              hipStream_t stream) {
    const float* x       = (const float*)d_in[0];
    const float* adj     = (const float*)d_in[1];
    const float* w_embed = (const float*)d_in[2];
    const float* b_embed = (const float*)d_in[3];
    const float* pos     = (const float*)d_in[4];
    const float* ln1_g   = (const float*)d_in[5];
    const float* ln1_b   = (const float*)d_in[6];
    const float* w_qkv   = (const float*)d_in[7];
    const float* b_qkv   = (const float*)d_in[8];
    const float* w_gate  = (const float*)d_in[9];
    const float* b_gate  = (const float*)d_in[10];
    const float* w_proj  = (const float*)d_in[11];
    const float* b_proj  = (const float*)d_in[12];
    const float* ln2_g   = (const float*)d_in[13];
    const float* ln2_b   = (const float*)d_in[14];
    const float* w_fc1   = (const float*)d_in[15];
    const float* b_fc1   = (const float*)d_in[16];
    const float* w_fc2   = (const float*)d_in[17];
    const float* b_fc2   = (const float*)d_in[18];
    const float* fn_g    = (const float*)d_in[19];
    const float* fn_b    = (const float*)d_in[20];
    unsigned short* ws   = (unsigned short*)d_ws;   // 2 MiB
    float* out = (float*)d_out;

    prep_wt<<<2048, 256, 0, stream>>>(w_qkv, w_proj, w_fc1, w_fc2, ws);
    pose3d_r19<<<1944, NTHREADS, 0, stream>>>(x, adj, w_embed, b_embed, pos,
        ln1_g, ln1_b, b_qkv, w_gate, b_gate, b_proj, ln2_g, ln2_b,
        b_fc1, b_fc2, fn_g, fn_b, ws, out);
}

// Round 14
// 1651.166 us; speedup vs baseline: 1.9831x; 1.6317x over previous
//
#include <hip/hip_runtime.h>
#include <math.h>

#define DEPTH 4
#define C 128
#define P 17
#define HID 256
#define SPB 4            // 4 samples per block = 2 independent 34-row groups
#define GR 34            // rows per group
#define ROWS 68          // SPB*P
#define MT 3             // M tiles per 34-row group (48 padded; clamped)
#define LS 132           // fp32 LDS row stride
#define QS 136           // bf16 q/k/v row stride (avoids pow2 bank conflicts)
#define SEGQ (ROWS*QS)   // 9248
#define AS 264           // hi/lo bf16 row stride (128 hi | 128 lo | 8 pad)
#define ARENA_N (ROWS*AS) // 17952 shorts
#define NTHREADS 256

// workspace: W^T planes, row-major N x K, bf16. hi plane [0,524288), lo at +524288.
#define WTQ 0
#define WTP 196608
#define WT1 262144
#define WT2 393216
#define LO_OFF 524288

typedef short short8 __attribute__((ext_vector_type(8)));
typedef float f32x4 __attribute__((ext_vector_type(4)));

__device__ __forceinline__ unsigned short f2bf(float f) {
    unsigned int u = __float_as_uint(f);
    u += 0x7FFFu + ((u >> 16) & 1u);
    return (unsigned short)(u >> 16);
}
__device__ __forceinline__ float bf2f(unsigned short s) {
    return __uint_as_float((unsigned int)s << 16);
}
__device__ __forceinline__ void unpack8(uint4 u, float* f) {
    f[0] = __uint_as_float(u.x << 16); f[1] = __uint_as_float(u.x & 0xffff0000u);
    f[2] = __uint_as_float(u.y << 16); f[3] = __uint_as_float(u.y & 0xffff0000u);
    f[4] = __uint_as_float(u.z << 16); f[5] = __uint_as_float(u.z & 0xffff0000u);
    f[6] = __uint_as_float(u.w << 16); f[7] = __uint_as_float(u.w & 0xffff0000u);
}

// ---------------- prep: transpose W (KxN) -> WT (NxK row-major), hi+lo ----------------
extern "C" __global__ void prep_wt(const float* __restrict__ wq, const float* __restrict__ wp,
                                   const float* __restrict__ w1, const float* __restrict__ w2,
                                   unsigned short* __restrict__ ws) {
    int idx = blockIdx.x * 256 + threadIdx.x;   // grid 2048*256 = 524288 exactly
    int rel = idx; const float* W; int K, N;
    if (rel < 196608)                  { W = wq; K = 128; N = 384; }
    else if ((rel -= 196608) < 65536)  { W = wp; K = 128; N = 128; }
    else if ((rel -= 65536) < 131072)  { W = w1; K = 128; N = 256; }
    else { rel -= 131072;                W = w2; K = 256; N = 128; }
    int per = K * N;
    int l = rel / per, r = rel % per;
    int n = r / K, k = r % K;          // WT[n][k], k fastest
    float wv = W[l * per + k * N + n];
    unsigned short h = f2bf(wv);
    ws[idx] = h;
    ws[idx + LO_OFF] = f2bf(wv - bf2f(h));
}

// -------- dual-group MFMA GEMM: shares B fragments across G0/G1 (2 indep chains) -----
// Local A-rows >= GR are clamped (outputs discarded by epilogue guard): no junk reads.
template<int NTW, int KS>
__device__ __forceinline__ void gemm_bt2(const unsigned short* A0, const unsigned short* A1,
        int astride, int aLoOff,
        const unsigned short* __restrict__ WT, int ldk, int ntoff, int ksoff,
        int wave, int lane, f32x4 (&acc0)[MT][NTW], f32x4 (&acc1)[MT][NTW])
{
    int m = lane & 15, q = lane >> 4;
    int arow[MT];
    #pragma unroll
    for (int mt = 0; mt < MT; ++mt) {
        int ar = mt * 16 + m;
        arow[mt] = (ar >= GR) ? (ar - 16) : ar;   // 34..47 -> 18..31
    }
    for (int ks = 0; ks < KS; ++ks) {
        short8 ah0[MT], al0[MT], ah1[MT], al1[MT];
        #pragma unroll
        for (int mt = 0; mt < MT; ++mt) {
            int off = arow[mt] * astride + ks * 32 + q * 8;
            ah0[mt] = *(const short8*)&A0[off];
            al0[mt] = *(const short8*)&A0[off + aLoOff];
            ah1[mt] = *(const short8*)&A1[off];
            al1[mt] = *(const short8*)&A1[off + aLoOff];
        }
        #pragma unroll
        for (int nt = 0; nt < NTW; ++nt) {
            int nrow = (ntoff + wave * NTW + nt) * 16 + m;
            const unsigned short* bp = WT + nrow * ldk + (ksoff + ks) * 32 + q * 8;
            short8 bh = *(const short8*)bp;
            short8 bl = *(const short8*)(bp + LO_OFF);
            #pragma unroll
            for (int mt = 0; mt < MT; ++mt) {
                acc0[mt][nt] = __builtin_amdgcn_mfma_f32_16x16x32_bf16(ah0[mt], bh, acc0[mt][nt], 0, 0, 0);
                acc1[mt][nt] = __builtin_amdgcn_mfma_f32_16x16x32_bf16(ah1[mt], bh, acc1[mt][nt], 0, 0, 0);
                acc0[mt][nt] = __builtin_amdgcn_mfma_f32_16x16x32_bf16(al0[mt], bh, acc0[mt][nt], 0, 0, 0);
                acc1[mt][nt] = __builtin_amdgcn_mfma_f32_16x16x32_bf16(al1[mt], bh, acc1[mt][nt], 0, 0, 0);
                acc0[mt][nt] = __builtin_amdgcn_mfma_f32_16x16x32_bf16(ah0[mt], bl, acc0[mt][nt], 0, 0, 0);
                acc1[mt][nt] = __builtin_amdgcn_mfma_f32_16x16x32_bf16(ah1[mt], bl, acc1[mt][nt], 0, 0, 0);
            }
        }
    }
}

template<int NTW>
__device__ __forceinline__ void zero_acc(f32x4 (&acc)[MT][NTW]) {
    #pragma unroll
    for (int mt = 0; mt < MT; ++mt)
        #pragma unroll
        for (int nt = 0; nt < NTW; ++nt) acc[mt][nt] = (f32x4){0.f, 0.f, 0.f, 0.f};
}

// MODE 0 = ln1 (+gate), 1 = ln2 -> hi/lo bf16 DIRECTLY into arena; 2 = final->out.
template<int MODE>
__device__ __forceinline__ void ln_stage(const float* h_s, unsigned short* dst, float* gate_s,
        const float* __restrict__ g, const float* __restrict__ b,
        const float* __restrict__ wg, float bgate,
        float* __restrict__ outp, int tok0, int wave, int lane)
{
    int half = lane >> 5, l2 = lane & 31;
    #pragma unroll
    for (int it = 0; it < 9; ++it) {
        int row = it * 8 + wave * 2 + half;   // 0..71, each once
        if (row < ROWS) {
            float4 v = *(const float4*)&h_s[row * LS + l2 * 4];
            float s  = v.x + v.y + v.z + v.w;
            float ss = v.x*v.x + v.y*v.y + v.z*v.z + v.w*v.w;
            #pragma unroll
            for (int o = 16; o > 0; o >>= 1) { s += __shfl_xor(s, o, 32); ss += __shfl_xor(ss, o, 32); }
            float mean = s * (1.f / C);
            float rstd = rsqrtf(ss * (1.f / C) - mean * mean + 1e-6f);
            float4 gg = *(const float4*)&g[l2 * 4];
            float4 bb = *(const float4*)&b[l2 * 4];
            float e0 = (v.x - mean) * rstd * gg.x + bb.x;
            float e1 = (v.y - mean) * rstd * gg.y + bb.y;
            float e2 = (v.z - mean) * rstd * gg.z + bb.z;
            float e3 = (v.w - mean) * rstd * gg.w + bb.w;
            if (MODE == 2) {
                *(float4*)&outp[(tok0 + row) * C + l2 * 4] = make_float4(e0, e1, e2, e3);
            } else {
                unsigned short h0 = f2bf(e0), h1 = f2bf(e1), h2 = f2bf(e2), h3 = f2bf(e3);
                *(ushort4*)&dst[row * AS + l2 * 4] = make_ushort4(h0, h1, h2, h3);
                *(ushort4*)&dst[row * AS + 128 + l2 * 4] =
                    make_ushort4(f2bf(e0 - bf2f(h0)), f2bf(e1 - bf2f(h1)),
                                 f2bf(e2 - bf2f(h2)), f2bf(e3 - bf2f(h3)));
                if (MODE == 0) {
                    float4 wv = *(const float4*)&wg[l2 * 4];
                    float gp = e0*wv.x + e1*wv.y + e2*wv.z + e3*wv.w;
                    #pragma unroll
                    for (int o = 16; o > 0; o >>= 1) gp += __shfl_xor(gp, o, 32);
                    if (l2 == 0) gate_s[row] = 1.f / (1.f + expf(-(gp + bgate)));
                }
            }
        }
    }
}

__device__ __forceinline__ void attn_store(float* ov, float inv, unsigned short* op) {
    short8 h0, h1, l0, l1;
    #pragma unroll
    for (int d = 0; d < 8; ++d) {
        float va = ov[d] * inv, vb = ov[d + 8] * inv;
        unsigned short ha = f2bf(va), hb = f2bf(vb);
        h0[d] = (short)ha; h1[d] = (short)hb;
        l0[d] = (short)f2bf(va - bf2f(ha));
        l1[d] = (short)f2bf(vb - bf2f(hb));
    }
    *(short8*)&op[0]   = h0;
    *(short8*)&op[8]   = h1;
    *(short8*)&op[128] = l0;
    *(short8*)&op[136] = l1;
}

extern "C" __global__ __launch_bounds__(NTHREADS, 1)
void pose3d_r20(const float* __restrict__ x, const float* __restrict__ adj,
                 const float* __restrict__ w_embed, const float* __restrict__ b_embed,
                 const float* __restrict__ pos,
                 const float* __restrict__ ln1_g, const float* __restrict__ ln1_b,
                 const float* __restrict__ b_qkv,
                 const float* __restrict__ w_gate, const float* __restrict__ b_gate,
                 const float* __restrict__ b_proj,
                 const float* __restrict__ ln2_g, const float* __restrict__ ln2_b,
                 const float* __restrict__ b_fc1, const float* __restrict__ b_fc2,
                 const float* __restrict__ fn_g, const float* __restrict__ fn_b,
                 const unsigned short* __restrict__ wsw,
                 float* __restrict__ out)
{
    __shared__ __align__(16) float h_s[ROWS * LS];            // residual fp32 (35904 B)
    __shared__ __align__(16) unsigned short u_s[3 * SEGQ];    // q,k,v bf16 (55488 B); t aliases here in MLP
    __shared__ __align__(16) unsigned short arena[ARENA_N];   // hi/lo A-operands (35904 B)
    __shared__ float adj_s[P * P];
    __shared__ float gate_s[ROWS];

    const int tid = threadIdx.x;
    const int wave = tid >> 6, lane = tid & 63;
    const int m16 = lane & 15, q4 = lane >> 4;
    const int blk = blockIdx.x;

    // ---- embed (68 rows) ----
    for (int idx = tid; idx < ROWS * C; idx += NTHREADS) {
        int row = idx >> 7, c = idx & 127;
        int s = row / 17, p = row % 17;
        int xb = (blk * SPB + s) * (P * 2) + p * 2;
        h_s[row * LS + c] = x[xb] * w_embed[c] + x[xb + 1] * w_embed[C + c]
                          + b_embed[c] + pos[p * C + c];
    }
    for (int idx = tid; idx < P * P; idx += NTHREADS) adj_s[idx] = adj[idx];
    __syncthreads();

    const unsigned short* const ar0 = arena;
    const unsigned short* const ar1 = arena + GR * AS;

    for (int i = 0; i < DEPTH; ++i) {
        // ---- LN1 + gate -> arena hi/lo directly (both groups) ----
        ln_stage<0>(h_s, arena, gate_s, ln1_g + i * C, ln1_b + i * C,
                    w_gate + i * C, b_gate[i], nullptr, 0, wave, lane);
        __syncthreads();

        // ---- qkv GEMM: 2 passes of NTW=3, dual-group shared-B ----
        #pragma unroll
        for (int pass = 0; pass < 2; ++pass) {
            f32x4 acc0[MT][3], acc1[MT][3];
            zero_acc<3>(acc0); zero_acc<3>(acc1);
            gemm_bt2<3, 4>(ar0, ar1, AS, 128, wsw + WTQ + i * 49152, 128, pass * 12, 0,
                           wave, lane, acc0, acc1);
            const float* bq = b_qkv + i * 384;
            #pragma unroll
            for (int nt = 0; nt < 3; ++nt) {
                int n = (pass * 12 + wave * 3 + nt) * 16 + m16;
                float bias = bq[n];
                int t = n >> 7, cc = n & 127;
                #pragma unroll
                for (int mt = 0; mt < MT; ++mt)
                    #pragma unroll
                    for (int r = 0; r < 4; ++r) {
                        int row = mt * 16 + q4 * 4 + r;
                        if (row < GR) {
                            u_s[t * SEGQ + row * QS + cc]        = f2bf(acc0[mt][nt][r] + bias);
                            u_s[t * SEGQ + (GR + row) * QS + cc] = f2bf(acc1[mt][nt][r] + bias);
                        }
                    }
            }
        }
        __syncthreads();

        // ---- attention (VALU): 544 tasks, two loops (r17 register profile);
        //      loop1: QK -> exp (no-max) -> Sv + sum; loop2: PV. K/V prefetch 1-ahead. ----
        for (int task = tid; task < 544; task += NTHREADS) {
            int n = task >> 5, sh = task & 31;       // n 0..16
            int s = sh >> 3, hh = sh & 7;            // s 0..3, hh 0..7
            int base = s * 17;
            float qv[16];
            { const uint4* qp = (const uint4*)&u_s[(base + n) * QS + hh * 16];
              unpack8(qp[0], qv); unpack8(qp[1], qv + 8); }
            float Sv[17]; float sum = 0.f;
            const unsigned short* kbase = &u_s[SEGQ + base * QS + hh * 16];
            uint4 k0 = *(const uint4*)kbase;
            uint4 k1 = *(const uint4*)(kbase + 8);
            #pragma unroll
            for (int mm = 0; mm < 17; ++mm) {
                uint4 p0 = k0, p1 = k1;
                if (mm < 16) {   // prefetch next K row while computing this one
                    p0 = *(const uint4*)(kbase + (mm + 1) * QS);
                    p1 = *(const uint4*)(kbase + (mm + 1) * QS + 8);
                }
                float kf[16]; unpack8(k0, kf); unpack8(k1, kf + 8);
                float a0 = qv[0]*kf[0] + qv[4]*kf[4] + qv[8]*kf[8]   + qv[12]*kf[12];
                float a1 = qv[1]*kf[1] + qv[5]*kf[5] + qv[9]*kf[9]   + qv[13]*kf[13];
                float a2 = qv[2]*kf[2] + qv[6]*kf[6] + qv[10]*kf[10] + qv[14]*kf[14];
                float a3 = qv[3]*kf[3] + qv[7]*kf[7] + qv[11]*kf[11] + qv[15]*kf[15];
                float acc = (a0 + a1) + (a2 + a3);
                float gt = gate_s[base + mm];
                float aa = acc * 0.25f * (1.f - gt) + adj_s[n * P + mm] * gt;
                float ea = __expf(aa);    // no-max softmax: scores bounded, fp32-safe
                Sv[mm] = ea; sum += ea;
                k0 = p0; k1 = p1;
            }
            float inv = 1.f / sum;
            float ov[16];
            #pragma unroll
            for (int d = 0; d < 16; ++d) ov[d] = 0.f;
            const unsigned short* vbase = &u_s[2 * SEGQ + base * QS + hh * 16];
            uint4 v0 = *(const uint4*)vbase;
            uint4 v1 = *(const uint4*)(vbase + 8);
            #pragma unroll
            for (int mm = 0; mm < 17; ++mm) {
                uint4 p0 = v0, p1 = v1;
                if (mm < 16) {   // prefetch next V row
                    p0 = *(const uint4*)(vbase + (mm + 1) * QS);
                    p1 = *(const uint4*)(vbase + (mm + 1) * QS + 8);
                }
                float vf[16]; unpack8(v0, vf); unpack8(v1, vf + 8);
                float w = Sv[mm];
                #pragma unroll
                for (int d = 0; d < 16; ++d) ov[d] += w * vf[d];
                v0 = p0; v1 = p1;
            }
            attn_store(ov, inv, &arena[(base + n) * AS + hh * 16]);
        }
        __syncthreads();

        // ---- proj GEMM dual-group (NTW=2) + residual into h_s ----
        {
            f32x4 acc0[MT][2], acc1[MT][2];
            zero_acc<2>(acc0); zero_acc<2>(acc1);
            gemm_bt2<2, 4>(ar0, ar1, AS, 128, wsw + WTP + i * 16384, 128, 0, 0,
                           wave, lane, acc0, acc1);
            const float* bp = b_proj + i * C;
            #pragma unroll
            for (int nt = 0; nt < 2; ++nt) {
                int n = (wave * 2 + nt) * 16 + m16;
                float bias = bp[n];
                #pragma unroll
                for (int mt = 0; mt < MT; ++mt)
                    #pragma unroll
                    for (int r = 0; r < 4; ++r) {
                        int row = mt * 16 + q4 * 4 + r;
                        if (row < GR) {
                            h_s[row * LS + n]        += acc0[mt][nt][r] + bias;
                            h_s[(GR + row) * LS + n] += acc1[mt][nt][r] + bias;
                        }
                    }
            }
        }
        __syncthreads();

        // ---- LN2 -> arena hi/lo directly ----
        ln_stage<1>(h_s, arena, gate_s, ln2_g + i * C, ln2_b + i * C,
                    nullptr, 0.f, nullptr, 0, wave, lane);
        __syncthreads();

        // ---- MLP dual-group (r14 proven 5-barrier form); t aliases u_s ----
        {
            const unsigned short* const t0 = u_s;
            const unsigned short* const t1 = u_s + GR * AS;
            f32x4 acc20[MT][2], acc21[MT][2];
            zero_acc<2>(acc20); zero_acc<2>(acc21);
            for (int hf = 0; hf < 2; ++hf) {
                f32x4 acc10[MT][2], acc11[MT][2];
                zero_acc<2>(acc10); zero_acc<2>(acc11);
                gemm_bt2<2, 4>(ar0, ar1, AS, 128, wsw + WT1 + i * 32768, 128, hf * 8, 0,
                               wave, lane, acc10, acc11);
                const float* b1 = b_fc1 + i * HID + hf * 128;
                #pragma unroll
                for (int nt = 0; nt < 2; ++nt) {
                    int nl = (wave * 2 + nt) * 16 + m16;
                    float bias = b1[nl];
                    #pragma unroll
                    for (int mt = 0; mt < MT; ++mt)
                        #pragma unroll
                        for (int r = 0; r < 4; ++r) {
                            int row = mt * 16 + q4 * 4 + r;
                            if (row < GR) {
                                float xx = acc10[mt][nt][r] + bias;
                                float ge = 0.5f * xx * (1.f + erff(xx * 0.70710678118654752f));
                                unsigned short hb = f2bf(ge);
                                u_s[row * AS + nl] = hb;
                                u_s[row * AS + 128 + nl] = f2bf(ge - bf2f(hb));
                                float xx1 = acc11[mt][nt][r] + bias;
                                float ge1 = 0.5f * xx1 * (1.f + erff(xx1 * 0.70710678118654752f));
                                unsigned short hb1 = f2bf(ge1);
                                u_s[(GR + row) * AS + nl] = hb1;
                                u_s[(GR + row) * AS + 128 + nl] = f2bf(ge1 - bf2f(hb1));
                            }
                        }
                }
                __syncthreads();   // t half visible
                gemm_bt2<2, 4>(t0, t1, AS, 128, wsw + WT2 + i * 32768, 256, 0, hf * 4,
                               wave, lane, acc20, acc21);
                __syncthreads();   // done reading t before next half overwrites
            }
            const float* b2 = b_fc2 + i * C;
            #pragma unroll
            for (int nt = 0; nt < 2; ++nt) {
                int n = (wave * 2 + nt) * 16 + m16;
                float bias = b2[n];
                #pragma unroll
                for (int mt = 0; mt < MT; ++mt)
                    #pragma unroll
                    for (int r = 0; r < 4; ++r) {
                        int row = mt * 16 + q4 * 4 + r;
                        if (row < GR) {
                            h_s[row * LS + n]        += acc20[mt][nt][r] + bias;
                            h_s[(GR + row) * LS + n] += acc21[mt][nt][r] + bias;
                        }
                    }
            }
        }
        __syncthreads();
    }

    // ---- final LN -> out ----
    ln_stage<2>(h_s, nullptr, nullptr, fn_g, fn_b, nullptr, 0.f, out, blk * ROWS, wave, lane);
}

extern "C" void kernel_launch(void* const* d_in, const int* in_sizes, int n_in,
                              void* d_out, int out_size, void* d_ws, size_t ws_size,
                              hipStream_t stream) {
    const float* x       = (const float*)d_in[0];
    const float* adj     = (const float*)d_in[1];
    const float* w_embed = (const float*)d_in[2];
    const float* b_embed = (const float*)d_in[3];
    const float* pos     = (const float*)d_in[4];
    const float* ln1_g   = (const float*)d_in[5];
    const float* ln1_b   = (const float*)d_in[6];
    const float* w_qkv   = (const float*)d_in[7];
    const float* b_qkv   = (const float*)d_in[8];
    const float* w_gate  = (const float*)d_in[9];
    const float* b_gate  = (const float*)d_in[10];
    const float* w_proj  = (const float*)d_in[11];
    const float* b_proj  = (const float*)d_in[12];
    const float* ln2_g   = (const float*)d_in[13];
    const float* ln2_b   = (const float*)d_in[14];
    const float* w_fc1   = (const float*)d_in[15];
    const float* b_fc1   = (const float*)d_in[16];
    const float* w_fc2   = (const float*)d_in[17];
    const float* b_fc2   = (const float*)d_in[18];
    const float* fn_g    = (const float*)d_in[19];
    const float* fn_b    = (const float*)d_in[20];
    unsigned short* ws   = (unsigned short*)d_ws;   // 2 MiB
    float* out = (float*)d_out;

    prep_wt<<<2048, 256, 0, stream>>>(w_qkv, w_proj, w_fc1, w_fc2, ws);
    pose3d_r20<<<1944, NTHREADS, 0, stream>>>(x, adj, w_embed, b_embed, pos,
        ln1_g, ln1_b, b_qkv, w_gate, b_gate, b_proj, ln2_g, ln2_b,
        b_fc1, b_fc2, fn_g, fn_b, ws, out);
}